// Round 4
// baseline (192.106 us; speedup 1.0000x reference)
//
#include <hip/hip_runtime.h>

// GCN layer: out = scatter_add(rows, vals[:,None] * embeds[cols]) over COO.
// N=50000, E=800000, D=96 (fp32 in/out; indices int32 per harness).
//
// R2: CSR-by-destination build + 32-lane per-node register reduction (1004->154us).
// R3: rank trick (hist atomic return = within-row rank) -> atomic-free scatter;
//     2x unrolled gather loop (154->109us). Accumulate is fetch-bound: 127MB
//     HBM at 3.3TB/s on the random embeds gather.
// R4: (a) bf16-compress embeds into ws each call (fused into hist kernel):
//     halves gather bytes, 9.6MB table L2-caches much better than 19.2MB.
//     (b) single-block 1024-thread scan replaces the 3-kernel scan chain.
//     Pipeline: memset + hist/compress + scan + scatter + accumulate.

#define DFEAT 96
#define SCAN_T 1024

__device__ inline unsigned bf16_rne(float x) {
    unsigned u = __float_as_uint(x);
    return (u + 0x7FFFu + ((u >> 16) & 1u)) >> 16;
}
__device__ inline float bf16_to_f32(unsigned short u) {
    return __uint_as_float((unsigned)u << 16);
}

// Blocks [0, histBlocks): counts[rows[i]]++ and record each edge's arrival rank.
// Blocks [histBlocks, ...): convert embeds fp32 -> bf16 (8 floats/thread).
__global__ void hist_rank_compress_kernel(const int* __restrict__ rows, int* __restrict__ counts,
                                          int* __restrict__ rank, int E, int histBlocks,
                                          const float* __restrict__ embeds,
                                          unsigned short* __restrict__ ebf, int nOct) {
    if ((int)blockIdx.x < histBlocks) {
        int i = blockIdx.x * blockDim.x + threadIdx.x;
        if (i < E) rank[i] = atomicAdd(&counts[rows[i]], 1);
    } else {
        int j = (blockIdx.x - histBlocks) * blockDim.x + threadIdx.x;
        if (j < nOct) {
            const float4* src = reinterpret_cast<const float4*>(embeds) + (size_t)j * 2;
            float4 f0 = src[0];
            float4 f1 = src[1];
            uint4 o;
            o.x = bf16_rne(f0.x) | (bf16_rne(f0.y) << 16);
            o.y = bf16_rne(f0.z) | (bf16_rne(f0.w) << 16);
            o.z = bf16_rne(f1.x) | (bf16_rne(f1.y) << 16);
            o.w = bf16_rne(f1.z) | (bf16_rne(f1.w) << 16);
            reinterpret_cast<uint4*>(ebf)[j] = o;
        }
    }
}

// Single-block exclusive scan of counts[N] -> offsets[N+1] (one 1024-thread WG).
__global__ void scan_full_kernel(const int* __restrict__ counts, int* __restrict__ offsets,
                                 int N, int E) {
    __shared__ int s[SCAN_T];
    int t = threadIdx.x;
    int C = (N + SCAN_T - 1) / SCAN_T;
    int base = t * C;
    int sum = 0;
    for (int j = 0; j < C; ++j) {
        int idx = base + j;
        if (idx < N) sum += counts[idx];
    }
    s[t] = sum;
    __syncthreads();
    for (int off = 1; off < SCAN_T; off <<= 1) {
        int v = (t >= off) ? s[t - off] : 0;
        __syncthreads();
        s[t] += v;
        __syncthreads();
    }
    int run = s[t] - sum;  // exclusive prefix of this thread's chunk
    for (int j = 0; j < C; ++j) {
        int idx = base + j;
        if (idx < N) {
            int c = counts[idx];
            offsets[idx] = run;
            run += c;
        }
    }
    if (t == SCAN_T - 1) offsets[N] = E;
}

// Atomic-free bucket scatter using the precomputed rank.
__global__ void scatter_norank_kernel(const int* __restrict__ rows, const int* __restrict__ cols,
                                      const float* __restrict__ vals, const int* __restrict__ offsets,
                                      const int* __restrict__ rank, int2* __restrict__ pairs, int E) {
    int i = blockIdx.x * blockDim.x + threadIdx.x;
    if (i < E) {
        int p = offsets[rows[i]] + rank[i];
        pairs[p] = make_int2(cols[i], __float_as_int(vals[i]));
    }
}

// One 32-lane half-wave per node: lane l owns features l, l+32, l+64. bf16 gather.
__global__ void accumulate_bf16_kernel(const int2* __restrict__ pairs, const int* __restrict__ offsets,
                                       const unsigned short* __restrict__ ebf,
                                       float* __restrict__ out, int N) {
    int node = blockIdx.x * (blockDim.x >> 5) + (threadIdx.x >> 5);
    int lane = threadIdx.x & 31;
    if (node >= N) return;
    int start = offsets[node];
    int end   = offsets[node + 1];
    float a0 = 0.f, a1 = 0.f, a2 = 0.f;
    int i = start;
    for (; i + 2 <= end; i += 2) {
        int2 p0 = pairs[i];
        int2 p1 = pairs[i + 1];
        const unsigned short* e0 = ebf + (size_t)p0.x * DFEAT;
        const unsigned short* e1 = ebf + (size_t)p1.x * DFEAT;
        float v0 = __int_as_float(p0.y);
        float v1 = __int_as_float(p1.y);
        float x0 = bf16_to_f32(e0[lane]), y0 = bf16_to_f32(e0[lane + 32]), z0 = bf16_to_f32(e0[lane + 64]);
        float x1 = bf16_to_f32(e1[lane]), y1 = bf16_to_f32(e1[lane + 32]), z1 = bf16_to_f32(e1[lane + 64]);
        a0 += v0 * x0; a1 += v0 * y0; a2 += v0 * z0;
        a0 += v1 * x1; a1 += v1 * y1; a2 += v1 * z1;
    }
    if (i < end) {
        int2 p = pairs[i];
        const unsigned short* e = ebf + (size_t)p.x * DFEAT;
        float v = __int_as_float(p.y);
        a0 += v * bf16_to_f32(e[lane]);
        a1 += v * bf16_to_f32(e[lane + 32]);
        a2 += v * bf16_to_f32(e[lane + 64]);
    }
    float* o = out + (size_t)node * DFEAT;
    o[lane]      = a0;
    o[lane + 32] = a1;
    o[lane + 64] = a2;
}

// ---- R3 fp32 fallback kernels (used if workspace too small for bf16 table) ----

__global__ void hist_rank_kernel(const int* __restrict__ rows, int* __restrict__ counts,
                                 int* __restrict__ rank, int E) {
    int i = blockIdx.x * blockDim.x + threadIdx.x;
    if (i < E) rank[i] = atomicAdd(&counts[rows[i]], 1);
}

__global__ void accumulate_kernel(const int2* __restrict__ pairs, const int* __restrict__ offsets,
                                  const float* __restrict__ embeds, float* __restrict__ out, int N) {
    int node = blockIdx.x * (blockDim.x >> 5) + (threadIdx.x >> 5);
    int lane = threadIdx.x & 31;
    if (node >= N) return;
    int start = offsets[node];
    int end   = offsets[node + 1];
    float a0 = 0.f, a1 = 0.f, a2 = 0.f;
    int i = start;
    for (; i + 2 <= end; i += 2) {
        int2 p0 = pairs[i];
        int2 p1 = pairs[i + 1];
        const float* e0 = embeds + (size_t)p0.x * DFEAT;
        const float* e1 = embeds + (size_t)p1.x * DFEAT;
        float v0 = __int_as_float(p0.y);
        float v1 = __int_as_float(p1.y);
        float x0 = e0[lane], y0 = e0[lane + 32], z0 = e0[lane + 64];
        float x1 = e1[lane], y1 = e1[lane + 32], z1 = e1[lane + 64];
        a0 += v0 * x0; a1 += v0 * y0; a2 += v0 * z0;
        a0 += v1 * x1; a1 += v1 * y1; a2 += v1 * z1;
    }
    if (i < end) {
        int2 p = pairs[i];
        const float* e = embeds + (size_t)p.x * DFEAT;
        float v = __int_as_float(p.y);
        a0 += v * e[lane]; a1 += v * e[lane + 32]; a2 += v * e[lane + 64];
    }
    float* o = out + (size_t)node * DFEAT;
    o[lane]      = a0;
    o[lane + 32] = a1;
    o[lane + 64] = a2;
}

// Last-resort fallback (R1 baseline).
__global__ void gcn_scatter_atomic_kernel(const int* __restrict__ rows, const int* __restrict__ cols,
                                          const float* __restrict__ vals, const float* __restrict__ embeds,
                                          float* __restrict__ out, int n_edges) {
    long long i = (long long)blockIdx.x * blockDim.x + threadIdx.x;
    long long total = (long long)n_edges * (DFEAT / 4);
    if (i >= total) return;
    int e = (int)(i / (DFEAT / 4));
    int q = (int)(i - (long long)e * (DFEAT / 4));
    int r = rows[e], c = cols[e];
    float v = vals[e];
    const float4* emb4 = reinterpret_cast<const float4*>(embeds + (long long)c * DFEAT);
    float4 x = emb4[q];
    float* o = out + (long long)r * DFEAT + q * 4;
    atomicAdd(o + 0, v * x.x);
    atomicAdd(o + 1, v * x.y);
    atomicAdd(o + 2, v * x.z);
    atomicAdd(o + 3, v * x.w);
}

extern "C" void kernel_launch(void* const* d_in, const int* in_sizes, int n_in,
                              void* d_out, int out_size, void* d_ws, size_t ws_size,
                              hipStream_t stream) {
    const int*   rows   = (const int*)d_in[0];
    const int*   cols   = (const int*)d_in[1];
    const float* vals   = (const float*)d_in[2];
    const float* embeds = (const float*)d_in[3];
    float*       out    = (float*)d_out;

    int E = in_sizes[0];
    int N = in_sizes[3] / DFEAT;
    int eb = (E + 255) / 256;

    // Workspace layout (16B-aligned sections):
    //   counts[N] | offsets[N+1] | rank[E] | pairs[E] (int2) | ebf16[N*DFEAT] (u16)
    size_t off_counts  = 0;
    size_t off_offsets = (off_counts + (size_t)N * 4 + 15) & ~(size_t)15;
    size_t off_rank    = (off_offsets + (size_t)(N + 1) * 4 + 15) & ~(size_t)15;
    size_t off_pairs   = (off_rank + (size_t)E * 4 + 15) & ~(size_t)15;
    size_t off_ebf     = (off_pairs + (size_t)E * 8 + 15) & ~(size_t)15;
    size_t need_bf16   = off_ebf + (size_t)N * DFEAT * 2;
    size_t need_fp32   = off_ebf;  // same layout minus the bf16 table

    if (ws_size >= need_fp32) {
        int* counts  = (int*)((char*)d_ws + off_counts);
        int* offsets = (int*)((char*)d_ws + off_offsets);
        int* rank    = (int*)((char*)d_ws + off_rank);
        int2* pairs  = (int2*)((char*)d_ws + off_pairs);
        unsigned short* ebf = (unsigned short*)((char*)d_ws + off_ebf);

        bool use_bf16 = (ws_size >= need_bf16);

        hipMemsetAsync(counts, 0, (size_t)N * sizeof(int), stream);

        if (use_bf16) {
            int nOct = (N * DFEAT) / 8;             // 8 floats per compress thread
            int cb = (nOct + 255) / 256;
            hist_rank_compress_kernel<<<eb + cb, 256, 0, stream>>>(
                rows, counts, rank, E, eb, embeds, ebf, nOct);
        } else {
            hist_rank_kernel<<<eb, 256, 0, stream>>>(rows, counts, rank, E);
        }

        scan_full_kernel<<<1, SCAN_T, 0, stream>>>(counts, offsets, N, E);
        scatter_norank_kernel<<<eb, 256, 0, stream>>>(rows, cols, vals, offsets, rank, pairs, E);

        int nodes_per_block = 256 / 32;  // 8
        int gb = (N + nodes_per_block - 1) / nodes_per_block;
        if (use_bf16) {
            accumulate_bf16_kernel<<<gb, 256, 0, stream>>>(pairs, offsets, ebf, out, N);
        } else {
            accumulate_kernel<<<gb, 256, 0, stream>>>(pairs, offsets, embeds, out, N);
        }
    } else {
        hipMemsetAsync(d_out, 0, (size_t)out_size * sizeof(float), stream);
        long long total = (long long)E * (DFEAT / 4);
        int block = 256;
        long long grid = (total + block - 1) / block;
        gcn_scatter_atomic_kernel<<<(int)grid, block, 0, stream>>>(rows, cols, vals, embeds, out, E);
    }
}

// Round 5
// 101.109 us; speedup vs baseline: 1.9000x; 1.9000x over previous
//
#include <hip/hip_runtime.h>

// GCN layer: out = scatter_add(rows, vals[:,None] * embeds[cols]) over COO.
// N=50000, E=800000, D=96 (fp32 in/out; indices int32 per harness).
//
// R2: CSR-by-destination build + 32-lane per-node register reduction (1004->154us).
// R3: rank trick -> atomic-free scatter; 2x unroll (154->109us).
// R4: bf16-compress embeds (absmax 0.0625 vs 0.295 thr, accumulate fetch halved)
//     BUT single-block scan regressed to 93us (1 CU, uncoalesced) -> 192us.
// R5: revert scan to R3's proven 3-kernel parallel chain; keep bf16 path;
//     4x unroll in the latency-bound accumulate.

#define DFEAT 96
#define SCAN_BS 256

__device__ inline unsigned bf16_rne(float x) {
    unsigned u = __float_as_uint(x);
    return (u + 0x7FFFu + ((u >> 16) & 1u)) >> 16;
}
__device__ inline float bf16_to_f32(unsigned short u) {
    return __uint_as_float((unsigned)u << 16);
}

// Blocks [0, histBlocks): counts[rows[i]]++ and record each edge's arrival rank.
// Blocks [histBlocks, ...): convert embeds fp32 -> bf16 (8 floats/thread).
__global__ void hist_rank_compress_kernel(const int* __restrict__ rows, int* __restrict__ counts,
                                          int* __restrict__ rank, int E, int histBlocks,
                                          const float* __restrict__ embeds,
                                          unsigned short* __restrict__ ebf, int nOct) {
    if ((int)blockIdx.x < histBlocks) {
        int i = blockIdx.x * blockDim.x + threadIdx.x;
        if (i < E) rank[i] = atomicAdd(&counts[rows[i]], 1);
    } else {
        int j = (blockIdx.x - histBlocks) * blockDim.x + threadIdx.x;
        if (j < nOct) {
            const float4* src = reinterpret_cast<const float4*>(embeds) + (size_t)j * 2;
            float4 f0 = src[0];
            float4 f1 = src[1];
            uint4 o;
            o.x = bf16_rne(f0.x) | (bf16_rne(f0.y) << 16);
            o.y = bf16_rne(f0.z) | (bf16_rne(f0.w) << 16);
            o.z = bf16_rne(f1.x) | (bf16_rne(f1.y) << 16);
            o.w = bf16_rne(f1.z) | (bf16_rne(f1.w) << 16);
            reinterpret_cast<uint4*>(ebf)[j] = o;
        }
    }
}

// Per-block scan; writes exclusive partials into offsets[], block sums out.
__global__ void scan_blocks_kernel(const int* __restrict__ counts, int* __restrict__ offsets,
                                   int* __restrict__ blockSums, int N) {
    __shared__ int s[SCAN_BS];
    int tid = threadIdx.x;
    int i = blockIdx.x * SCAN_BS + tid;
    int v = (i < N) ? counts[i] : 0;
    s[tid] = v;
    __syncthreads();
    for (int off = 1; off < SCAN_BS; off <<= 1) {
        int t = (tid >= off) ? s[tid - off] : 0;
        __syncthreads();
        s[tid] += t;
        __syncthreads();
    }
    if (i < N) offsets[i] = s[tid] - v;   // exclusive within block
    if (tid == SCAN_BS - 1) blockSums[blockIdx.x] = s[tid];
}

// Single-block exclusive scan of the block sums (nb <= SCAN_BS).
__global__ void scan_sums_kernel(const int* __restrict__ blockSums, int* __restrict__ blockOffs, int nb) {
    __shared__ int s[SCAN_BS];
    int tid = threadIdx.x;
    int v = (tid < nb) ? blockSums[tid] : 0;
    s[tid] = v;
    __syncthreads();
    for (int off = 1; off < SCAN_BS; off <<= 1) {
        int t = (tid >= off) ? s[tid - off] : 0;
        __syncthreads();
        s[tid] += t;
        __syncthreads();
    }
    if (tid < nb) blockOffs[tid] = s[tid] - v;
}

__global__ void add_offsets_kernel(int* __restrict__ offsets, const int* __restrict__ blockOffs,
                                   int N, int E) {
    int i = blockIdx.x * blockDim.x + threadIdx.x;
    if (i < N) offsets[i] += blockOffs[i / SCAN_BS];
    if (i == 0) offsets[N] = E;
}

// Atomic-free bucket scatter using the precomputed rank.
__global__ void scatter_norank_kernel(const int* __restrict__ rows, const int* __restrict__ cols,
                                      const float* __restrict__ vals, const int* __restrict__ offsets,
                                      const int* __restrict__ rank, int2* __restrict__ pairs, int E) {
    int i = blockIdx.x * blockDim.x + threadIdx.x;
    if (i < E) {
        int p = offsets[rows[i]] + rank[i];
        pairs[p] = make_int2(cols[i], __float_as_int(vals[i]));
    }
}

// One 32-lane half-wave per node: lane l owns features l, l+32, l+64.
// bf16 gather, 4x unrolled (latency-bound: keep more gathers in flight).
__global__ void accumulate_bf16_kernel(const int2* __restrict__ pairs, const int* __restrict__ offsets,
                                       const unsigned short* __restrict__ ebf,
                                       float* __restrict__ out, int N) {
    int node = blockIdx.x * (blockDim.x >> 5) + (threadIdx.x >> 5);
    int lane = threadIdx.x & 31;
    if (node >= N) return;
    int start = offsets[node];
    int end   = offsets[node + 1];
    float a0 = 0.f, a1 = 0.f, a2 = 0.f;
    int i = start;
    for (; i + 4 <= end; i += 4) {
        int2 p0 = pairs[i];
        int2 p1 = pairs[i + 1];
        int2 p2 = pairs[i + 2];
        int2 p3 = pairs[i + 3];
        const unsigned short* e0 = ebf + (size_t)p0.x * DFEAT;
        const unsigned short* e1 = ebf + (size_t)p1.x * DFEAT;
        const unsigned short* e2 = ebf + (size_t)p2.x * DFEAT;
        const unsigned short* e3 = ebf + (size_t)p3.x * DFEAT;
        float v0 = __int_as_float(p0.y), v1 = __int_as_float(p1.y);
        float v2 = __int_as_float(p2.y), v3 = __int_as_float(p3.y);
        float x0 = bf16_to_f32(e0[lane]), y0 = bf16_to_f32(e0[lane + 32]), z0 = bf16_to_f32(e0[lane + 64]);
        float x1 = bf16_to_f32(e1[lane]), y1 = bf16_to_f32(e1[lane + 32]), z1 = bf16_to_f32(e1[lane + 64]);
        float x2 = bf16_to_f32(e2[lane]), y2 = bf16_to_f32(e2[lane + 32]), z2 = bf16_to_f32(e2[lane + 64]);
        float x3 = bf16_to_f32(e3[lane]), y3 = bf16_to_f32(e3[lane + 32]), z3 = bf16_to_f32(e3[lane + 64]);
        a0 += v0 * x0; a1 += v0 * y0; a2 += v0 * z0;
        a0 += v1 * x1; a1 += v1 * y1; a2 += v1 * z1;
        a0 += v2 * x2; a1 += v2 * y2; a2 += v2 * z2;
        a0 += v3 * x3; a1 += v3 * y3; a2 += v3 * z3;
    }
    for (; i < end; ++i) {
        int2 p = pairs[i];
        const unsigned short* e = ebf + (size_t)p.x * DFEAT;
        float v = __int_as_float(p.y);
        a0 += v * bf16_to_f32(e[lane]);
        a1 += v * bf16_to_f32(e[lane + 32]);
        a2 += v * bf16_to_f32(e[lane + 64]);
    }
    float* o = out + (size_t)node * DFEAT;
    o[lane]      = a0;
    o[lane + 32] = a1;
    o[lane + 64] = a2;
}

// ---- fallbacks ----

__global__ void hist_rank_kernel(const int* __restrict__ rows, int* __restrict__ counts,
                                 int* __restrict__ rank, int E) {
    int i = blockIdx.x * blockDim.x + threadIdx.x;
    if (i < E) rank[i] = atomicAdd(&counts[rows[i]], 1);
}

__global__ void accumulate_kernel(const int2* __restrict__ pairs, const int* __restrict__ offsets,
                                  const float* __restrict__ embeds, float* __restrict__ out, int N) {
    int node = blockIdx.x * (blockDim.x >> 5) + (threadIdx.x >> 5);
    int lane = threadIdx.x & 31;
    if (node >= N) return;
    int start = offsets[node];
    int end   = offsets[node + 1];
    float a0 = 0.f, a1 = 0.f, a2 = 0.f;
    int i = start;
    for (; i + 2 <= end; i += 2) {
        int2 p0 = pairs[i];
        int2 p1 = pairs[i + 1];
        const float* e0 = embeds + (size_t)p0.x * DFEAT;
        const float* e1 = embeds + (size_t)p1.x * DFEAT;
        float v0 = __int_as_float(p0.y);
        float v1 = __int_as_float(p1.y);
        float x0 = e0[lane], y0 = e0[lane + 32], z0 = e0[lane + 64];
        float x1 = e1[lane], y1 = e1[lane + 32], z1 = e1[lane + 64];
        a0 += v0 * x0; a1 += v0 * y0; a2 += v0 * z0;
        a0 += v1 * x1; a1 += v1 * y1; a2 += v1 * z1;
    }
    if (i < end) {
        int2 p = pairs[i];
        const float* e = embeds + (size_t)p.x * DFEAT;
        float v = __int_as_float(p.y);
        a0 += v * e[lane]; a1 += v * e[lane + 32]; a2 += v * e[lane + 64];
    }
    float* o = out + (size_t)node * DFEAT;
    o[lane]      = a0;
    o[lane + 32] = a1;
    o[lane + 64] = a2;
}

__global__ void gcn_scatter_atomic_kernel(const int* __restrict__ rows, const int* __restrict__ cols,
                                          const float* __restrict__ vals, const float* __restrict__ embeds,
                                          float* __restrict__ out, int n_edges) {
    long long i = (long long)blockIdx.x * blockDim.x + threadIdx.x;
    long long total = (long long)n_edges * (DFEAT / 4);
    if (i >= total) return;
    int e = (int)(i / (DFEAT / 4));
    int q = (int)(i - (long long)e * (DFEAT / 4));
    int r = rows[e], c = cols[e];
    float v = vals[e];
    const float4* emb4 = reinterpret_cast<const float4*>(embeds + (long long)c * DFEAT);
    float4 x = emb4[q];
    float* o = out + (long long)r * DFEAT + q * 4;
    atomicAdd(o + 0, v * x.x);
    atomicAdd(o + 1, v * x.y);
    atomicAdd(o + 2, v * x.z);
    atomicAdd(o + 3, v * x.w);
}

extern "C" void kernel_launch(void* const* d_in, const int* in_sizes, int n_in,
                              void* d_out, int out_size, void* d_ws, size_t ws_size,
                              hipStream_t stream) {
    const int*   rows   = (const int*)d_in[0];
    const int*   cols   = (const int*)d_in[1];
    const float* vals   = (const float*)d_in[2];
    const float* embeds = (const float*)d_in[3];
    float*       out    = (float*)d_out;

    int E = in_sizes[0];
    int N = in_sizes[3] / DFEAT;
    int eb = (E + 255) / 256;
    int nb = (N + SCAN_BS - 1) / SCAN_BS;   // scan blocks (196 for N=50000)

    // Workspace layout (16B-aligned sections):
    //   counts[N] | offsets[N+1] | blockSums[nb] | blockOffs[nb] | rank[E]
    //   | pairs[E] (int2) | ebf16[N*DFEAT] (u16)
    size_t off_counts  = 0;
    size_t off_offsets = (off_counts + (size_t)N * 4 + 15) & ~(size_t)15;
    size_t off_bsums   = (off_offsets + (size_t)(N + 1) * 4 + 15) & ~(size_t)15;
    size_t off_boffs   = (off_bsums + (size_t)nb * 4 + 15) & ~(size_t)15;
    size_t off_rank    = (off_boffs + (size_t)nb * 4 + 15) & ~(size_t)15;
    size_t off_pairs   = (off_rank + (size_t)E * 4 + 15) & ~(size_t)15;
    size_t off_ebf     = (off_pairs + (size_t)E * 8 + 15) & ~(size_t)15;
    size_t need_bf16   = off_ebf + (size_t)N * DFEAT * 2;
    size_t need_fp32   = off_ebf;

    if (nb <= SCAN_BS && ws_size >= need_fp32) {
        int*  counts    = (int*)((char*)d_ws + off_counts);
        int*  offsets   = (int*)((char*)d_ws + off_offsets);
        int*  blockSums = (int*)((char*)d_ws + off_bsums);
        int*  blockOffs = (int*)((char*)d_ws + off_boffs);
        int*  rank      = (int*)((char*)d_ws + off_rank);
        int2* pairs     = (int2*)((char*)d_ws + off_pairs);
        unsigned short* ebf = (unsigned short*)((char*)d_ws + off_ebf);

        bool use_bf16 = (ws_size >= need_bf16);

        hipMemsetAsync(counts, 0, (size_t)N * sizeof(int), stream);

        if (use_bf16) {
            int nOct = (N * DFEAT) / 8;             // 8 floats per compress thread
            int cb = (nOct + 255) / 256;
            hist_rank_compress_kernel<<<eb + cb, 256, 0, stream>>>(
                rows, counts, rank, E, eb, embeds, ebf, nOct);
        } else {
            hist_rank_kernel<<<eb, 256, 0, stream>>>(rows, counts, rank, E);
        }

        scan_blocks_kernel<<<nb, SCAN_BS, 0, stream>>>(counts, offsets, blockSums, N);
        scan_sums_kernel<<<1, SCAN_BS, 0, stream>>>(blockSums, blockOffs, nb);
        add_offsets_kernel<<<(N + 255) / 256, 256, 0, stream>>>(offsets, blockOffs, N, E);

        scatter_norank_kernel<<<eb, 256, 0, stream>>>(rows, cols, vals, offsets, rank, pairs, E);

        int nodes_per_block = 256 / 32;  // 8
        int gb = (N + nodes_per_block - 1) / nodes_per_block;
        if (use_bf16) {
            accumulate_bf16_kernel<<<gb, 256, 0, stream>>>(pairs, offsets, ebf, out, N);
        } else {
            accumulate_kernel<<<gb, 256, 0, stream>>>(pairs, offsets, embeds, out, N);
        }
    } else {
        hipMemsetAsync(d_out, 0, (size_t)out_size * sizeof(float), stream);
        long long total = (long long)E * (DFEAT / 4);
        int block = 256;
        long long grid = (total + block - 1) / block;
        gcn_scatter_atomic_kernel<<<(int)grid, block, 0, stream>>>(rows, cols, vals, embeds, out, E);
    }
}